// Round 2
// baseline (281.297 us; speedup 1.0000x reference)
//
#include <hip/hip_runtime.h>
#include <stdint.h>

#define DD 512
#define HH 8
#define DOO 64
#define ALPHA 0.2f

typedef __attribute__((ext_vector_type(8))) short short8;
typedef __attribute__((ext_vector_type(4))) float floatx4;
typedef __attribute__((ext_vector_type(4))) unsigned short u16x4;
typedef unsigned short u16;

static __device__ __forceinline__ float bf2f(u16 u){
  union { unsigned int u; float f; } c; c.u = ((unsigned int)u) << 16; return c.f;
}
static __device__ __forceinline__ u16 f2bf(float f){
  union { float f; unsigned int u; } c; c.f = f;
  unsigned int u = c.u;
  unsigned int r = (u + 0x7FFFu + ((u >> 16) & 1u)) >> 16;
  return (u16)r;
}
static __device__ __forceinline__ float leaky(float s){ return (s >= 0.f) ? s : ALPHA * s; }
static __device__ __forceinline__ float elu(float v){ return (v > 0.f) ? v : (__expf(v) - 1.f); }

// (z0c, z1c) bf16 pair from two edges' dwords: lo16 = z0's bf16, hi16 = z1's bf16
// v_perm pool: sel 0-3 -> src1 bytes, 4-7 -> src0 bytes
#define PERM_LO 0x01000504u
#define PERM_HI 0x03020706u

#define DOT2(accv, pairv, wv) \
  asm("v_dot2_f32_bf16 %0, %1, %2, %0" : "+v"(accv) : "v"(pairv), "v"(wv))

#define DOTS8(ZA, ZB, AQ) do{ unsigned pr_; \
  pr_=__builtin_amdgcn_perm((ZA).x,(ZB).x,PERM_LO); DOT2(acc[0],pr_,(AQ)); \
  pr_=__builtin_amdgcn_perm((ZA).x,(ZB).x,PERM_HI); DOT2(acc[1],pr_,(AQ)); \
  pr_=__builtin_amdgcn_perm((ZA).y,(ZB).y,PERM_LO); DOT2(acc[2],pr_,(AQ)); \
  pr_=__builtin_amdgcn_perm((ZA).y,(ZB).y,PERM_HI); DOT2(acc[3],pr_,(AQ)); \
  pr_=__builtin_amdgcn_perm((ZA).z,(ZB).z,PERM_LO); DOT2(acc[4],pr_,(AQ)); \
  pr_=__builtin_amdgcn_perm((ZA).z,(ZB).z,PERM_HI); DOT2(acc[5],pr_,(AQ)); \
  pr_=__builtin_amdgcn_perm((ZA).w,(ZB).w,PERM_LO); DOT2(acc[6],pr_,(AQ)); \
  pr_=__builtin_amdgcn_perm((ZA).w,(ZB).w,PERM_HI); DOT2(acc[7],pr_,(AQ)); \
}while(0)

#define GLOAD_LDS16(g, l) \
  __builtin_amdgcn_global_load_lds((const __attribute__((address_space(1))) void*)(g), \
                                   (__attribute__((address_space(3))) void*)(l), 16, 0, 0)

// whole-wave coalesced 1KB row gather: lane covers cols [lane*8, lane*8+8)
static __device__ __forceinline__ uint4 rowl(const u16* __restrict__ zp, int s, int lane){
  return ((const uint4*)(zp + ((size_t)(unsigned)s << 9)))[lane];
}

// ---------------- fused prep: x->bf16, W1 transpose, Wout transpose, degree count ----------------
__global__ void k_prep(const float* __restrict__ h, u16* __restrict__ xb,
                       const float* __restrict__ W1, u16* __restrict__ wbt1,
                       const float* __restrict__ Wout, u16* __restrict__ wbt2,
                       const int* __restrict__ dst, int* deg,
                       int n4, int E){
  int i = blockIdx.x * blockDim.x + threadIdx.x;
  if (i < n4){
    float4 v = ((const float4*)h)[i];
    u16x4 o;
    o[0] = f2bf(v.x); o[1] = f2bf(v.y); o[2] = f2bf(v.z); o[3] = f2bf(v.w);
    ((u16x4*)xb)[i] = o;
    return;
  }
  i -= n4;
  if (i < HH * DD * DOO / 8){
    int idx0 = i * 8;
    #pragma unroll
    for (int t = 0; t < 8; t++){
      int idx = idx0 + t;
      int hh = idx >> 15;
      int rem = idx & 32767;
      int k = rem >> 6;
      int dd = rem & 63;
      wbt1[(hh * 64 + dd) * DD + k] = f2bf(W1[idx]);
    }
    return;
  }
  i -= HH * DD * DOO / 8;
  if (i < DD * DD){
    int k = i >> 9, n = i & 511;
    wbt2[n * DD + k] = f2bf(Wout[i]);
    return;
  }
  i -= DD * DD;
  if (i < E) atomicAdd(&deg[dst[i]], 1);
}

// ---------------- CSR build (degrees padded to multiple of 4: pairs aligned, no loop masks) ----------------
__global__ void k_scan(const int* __restrict__ deg, int* __restrict__ off, int N){
  __shared__ int sm[1024];
  int tid = threadIdx.x;
  const int per = 16;
  int base = tid * per;
  int loc[per];
  int t = 0;
  #pragma unroll
  for (int i = 0; i < per; i++){
    int v = (base + i < N) ? deg[base + i] : 0;
    v = (v + 3) & ~3;                       // pad each node's edge list to multiple of 4
    loc[i] = v; t += v;
  }
  sm[tid] = t; __syncthreads();
  for (int o = 1; o < 1024; o <<= 1){
    int v = 0;
    if (tid >= o) v = sm[tid - o];
    __syncthreads();
    sm[tid] += v;
    __syncthreads();
  }
  int run = sm[tid] - t;
  #pragma unroll
  for (int i = 0; i < per; i++){ if (base + i < N) off[base + i] = run; run += loc[i]; }
  if (tid == 1023) off[N] = run;
}

__global__ void k_scatter(const int* __restrict__ src, const int* __restrict__ dst,
                          const int* __restrict__ off, int* cursor, int* __restrict__ csr,
                          int E, int N){
  int i = blockIdx.x * blockDim.x + threadIdx.x;
  if (i < 256){                             // zero the prefetch-overrun slack past off[N]
    csr[off[N] + i] = 0;
  }
  if (i < E){
    int d = dst[i];
    int p = atomicAdd(&cursor[d], 1);
    csr[off[d] + p] = src[i];
  }
}

// ---------------- bf16 MFMA GEMM: BK=64, XOR-swizzled LDS, n-fastest grid ----------------
__global__ __launch_bounds__(256) void k_gemm(const u16* __restrict__ A,
                                              const u16* __restrict__ BT,
                                              u16* __restrict__ C, int M){
  __shared__ __attribute__((aligned(16))) u16 As[128 * 64];
  __shared__ __attribute__((aligned(16))) u16 Bs[128 * 64];
  const int tid = threadIdx.x;
  const int wid = tid >> 6, lane = tid & 63;
  const int n0 = blockIdx.x * 128, m0 = blockIdx.y * 128;
  const int wr = wid >> 1, wc = wid & 1;
  const int row16 = lane & 15, kg = lane >> 4;
  floatx4 acc[4][4];
  #pragma unroll
  for (int i = 0; i < 4; i++)
    #pragma unroll
    for (int j = 0; j < 4; j++) acc[i][j] = (floatx4)0.0f;

  for (int kt = 0; kt < DD; kt += 64){
    #pragma unroll
    for (int i = 0; i < 4; i++){
      int chunk = i * 256 + tid;          // LDS granule 0..1023 (linear dest)
      int m = chunk >> 3, g = chunk & 7;
      int gs = g ^ (m & 7);               // inverse-swizzled global source granule
      GLOAD_LDS16(A + (size_t)(m0 + m) * DD + kt + gs * 8, &As[chunk * 8]);
      GLOAD_LDS16(BT + (size_t)(n0 + m) * DD + kt + gs * 8, &Bs[chunk * 8]);
    }
    __syncthreads();
    short8 af[4][2], bf[4][2];
    #pragma unroll
    for (int mi = 0; mi < 4; mi++)
      #pragma unroll
      for (int kk = 0; kk < 2; kk++){
        int row = wr * 64 + mi * 16 + row16;
        int gr = (kk * 4 + kg) ^ (row & 7);
        af[mi][kk] = *(const short8*)(&As[(row * 8 + gr) * 8]);
      }
    #pragma unroll
    for (int ni = 0; ni < 4; ni++)
      #pragma unroll
      for (int kk = 0; kk < 2; kk++){
        int row = wc * 64 + ni * 16 + row16;
        int gr = (kk * 4 + kg) ^ (row & 7);
        bf[ni][kk] = *(const short8*)(&Bs[(row * 8 + gr) * 8]);
      }
    #pragma unroll
    for (int kk = 0; kk < 2; kk++)
      #pragma unroll
      for (int mi = 0; mi < 4; mi++)
        #pragma unroll
        for (int ni = 0; ni < 4; ni++)
          acc[mi][ni] = __builtin_amdgcn_mfma_f32_16x16x32_bf16(af[mi][kk], bf[ni][kk], acc[mi][ni], 0, 0, 0);
    __syncthreads();
  }
  #pragma unroll
  for (int mi = 0; mi < 4; mi++)
    #pragma unroll
    for (int ni = 0; ni < 4; ni++)
      #pragma unroll
      for (int j = 0; j < 4; j++){
        int r = m0 + wr * 64 + mi * 16 + kg * 4 + j;
        int c = n0 + wc * 64 + ni * 16 + row16;
        C[(size_t)r * DD + c] = f2bf(acc[mi][ni][j]);
      }
}

// ---------------- attention scores ----------------
__global__ void k_scores1(const u16* __restrict__ z, const float* __restrict__ a1,
                          float* __restrict__ es, float* __restrict__ ed, int N){
  int wid = threadIdx.x >> 6, lane = threadIdx.x & 63;
  int n = blockIdx.x * 4 + wid;
  if (n >= N) return;
  int h = lane >> 3, j8 = lane & 7;
  short8 zv = *(const short8*)(z + (size_t)n * DD + lane * 8);
  float esv = 0.f, edv = 0.f;
  #pragma unroll
  for (int t = 0; t < 8; t++){
    float f = bf2f((u16)zv[t]);
    esv += f * a1[h * 128 + j8 * 8 + t];
    edv += f * a1[h * 128 + 64 + j8 * 8 + t];
  }
  #pragma unroll
  for (int d2 = 1; d2 < 8; d2 <<= 1){ esv += __shfl_xor(esv, d2); edv += __shfl_xor(edv, d2); }
  if (j8 == 0){ es[n * 8 + h] = esv; ed[n * 8 + h] = edv; }
}

__global__ void k_scores2(const u16* __restrict__ z, const float* __restrict__ aout,
                          float* __restrict__ es, float* __restrict__ ed, int N){
  int wid = threadIdx.x >> 6, lane = threadIdx.x & 63;
  int n = blockIdx.x * 4 + wid;
  if (n >= N) return;
  short8 zv = *(const short8*)(z + (size_t)n * DD + lane * 8);
  float esv = 0.f, edv = 0.f;
  #pragma unroll
  for (int t = 0; t < 8; t++){
    float f = bf2f((u16)zv[t]);
    esv += f * aout[lane * 8 + t];
    edv += f * aout[512 + lane * 8 + t];
  }
  #pragma unroll
  for (int d2 = 1; d2 < 64; d2 <<= 1){ esv += __shfl_xor(esv, d2); edv += __shfl_xor(edv, d2); }
  if (lane == 0){ es[n] = esv; ed[n] = edv; }
}

// ---------------- edge weights, hoisted out of aggregation ----------------
// One wave per node. w = exp(leaky(es[src]+ed[n])) per head; pack CSR pairs as bf16x2
// in [pair][head] layout (coalesced dword per lane in agg); den in f32; pads w=0 src=0.
__global__ void k_edgew1(const float* __restrict__ es, const float* __restrict__ ed,
                         const int* __restrict__ off, const int* __restrict__ deg,
                         int* __restrict__ csr, unsigned* __restrict__ wp,
                         float* __restrict__ den1, int N){
  int wid = threadIdx.x >> 6, lane = threadIdx.x & 63;
  int n = blockIdx.x * 4 + wid;
  if (n >= N) return;
  int o0 = off[n], cntp = off[n + 1] - o0, cnt = deg[n];
  float edh[8];
  {
    float4 d0 = *(const float4*)(ed + (size_t)n * 8);
    float4 d1 = *(const float4*)(ed + (size_t)n * 8 + 4);
    edh[0]=d0.x; edh[1]=d0.y; edh[2]=d0.z; edh[3]=d0.w;
    edh[4]=d1.x; edh[5]=d1.y; edh[6]=d1.z; edh[7]=d1.w;
  }
  float den[8];
  #pragma unroll
  for (int h = 0; h < 8; h++) den[h] = 0.f;
  for (int base = 0; base < cntp; base += 64){
    int e = base + lane;
    float wv[8];
    if (e < cnt){
      int s = csr[o0 + e];
      float4 e0 = *(const float4*)(es + (size_t)s * 8);
      float4 e1 = *(const float4*)(es + (size_t)s * 8 + 4);
      float ev[8] = {e0.x, e0.y, e0.z, e0.w, e1.x, e1.y, e1.z, e1.w};
      #pragma unroll
      for (int h = 0; h < 8; h++){
        float w = __expf(leaky(ev[h] + edh[h]));
        wv[h] = w; den[h] += w;
      }
    } else {
      if (e < cntp) csr[o0 + e] = 0;      // pad slot: valid gather target, zero weight
      #pragma unroll
      for (int h = 0; h < 8; h++) wv[h] = 0.f;
    }
    unsigned pk[8];
    #pragma unroll
    for (int h = 0; h < 8; h++){
      float wn = __shfl_down(wv[h], 1);
      asm("v_cvt_pk_bf16_f32 %0, %1, %2" : "=v"(pk[h]) : "v"(wv[h]), "v"(wn));
    }
    if (!(lane & 1) && e < cntp){
      size_t q = (size_t)((o0 + e) >> 1) * 8;
      uint4 v0; v0.x = pk[0]; v0.y = pk[1]; v0.z = pk[2]; v0.w = pk[3];
      uint4 v1; v1.x = pk[4]; v1.y = pk[5]; v1.z = pk[6]; v1.w = pk[7];
      *(uint4*)(wp + q) = v0;
      *(uint4*)(wp + q + 4) = v1;
    }
  }
  #pragma unroll
  for (int h = 0; h < 8; h++){
    float d = den[h];
    #pragma unroll
    for (int d2 = 1; d2 < 64; d2 <<= 1) d += __shfl_xor(d, d2);
    if (lane == 0) den1[(size_t)n * 8 + h] = d;
  }
}

__global__ void k_edgew2(const float* __restrict__ es, const float* __restrict__ ed,
                         const int* __restrict__ off, const int* __restrict__ deg,
                         int* __restrict__ csr, unsigned* __restrict__ wp,
                         float* __restrict__ den2, int N){
  int wid = threadIdx.x >> 6, lane = threadIdx.x & 63;
  int n = blockIdx.x * 4 + wid;
  if (n >= N) return;
  int o0 = off[n], cntp = off[n + 1] - o0, cnt = deg[n];
  float edn = ed[n];
  float dsum = 0.f;
  for (int base = 0; base < cntp; base += 64){
    int e = base + lane;
    float w = 0.f;
    if (e < cnt){
      int s = csr[o0 + e];
      w = __expf(leaky(es[s] + edn));
      dsum += w;
    } else if (e < cntp){
      csr[o0 + e] = 0;
    }
    float wn = __shfl_down(w, 1);
    if (!(lane & 1) && e < cntp){
      unsigned pk;
      asm("v_cvt_pk_bf16_f32 %0, %1, %2" : "=v"(pk) : "v"(w), "v"(wn));
      wp[(o0 + e) >> 1] = pk;
    }
  }
  #pragma unroll
  for (int d2 = 1; d2 < 64; d2 <<= 1) dsum += __shfl_xor(dsum, d2);
  if (lane == 0) den2[n] = dsum;
}

// ---------------- single-pass aggregation: whole wave per edge-pair, all 512 cols ----------------
// Wave per node. Lane l owns cols [8l, 8l+8). Pair indices are wave-uniform -> csr via s_load,
// row bases in SALU, gathers are fully-coalesced 1KB saddr loads. No masks (CSR padded to
// mult-of-4 edges), no cross-lane acc reduce. 2 pairs/iter, z double-buffered, csr 2-ahead.
__global__ __launch_bounds__(256) void k_agg1(const u16* __restrict__ z,
    const unsigned* __restrict__ wp, const float* __restrict__ den1,
    const int* __restrict__ off, const int* __restrict__ csr,
    u16* __restrict__ hcat, int N){
  int wid = __builtin_amdgcn_readfirstlane(threadIdx.x >> 6);
  int lane = threadIdx.x & 63;
  int n = blockIdx.x * 4 + wid;
  if (n >= N) return;
  int o0 = off[n];
  int itn = (off[n + 1] - o0) >> 2;        // 4 edges (2 pairs) per iteration, exact
  const int4* cp4 = (const int4*)(csr + o0);
  int pb = o0 >> 1;
  int head = lane >> 3;
  const unsigned* wpb = wp + (size_t)pb * 8 + head;   // [pair][head] layout
  float acc[8];
  #pragma unroll
  for (int j = 0; j < 8; j++) acc[j] = 0.f;

  uint4 zA0, zA1, zB0, zB1;
  unsigned aqA, aqB;
  int4 c1;
  {
    int4 c0 = cp4[0];
    c1 = cp4[1];
    zA0 = rowl(z, c0.x, lane); zA1 = rowl(z, c0.y, lane);
    zB0 = rowl(z, c0.z, lane); zB1 = rowl(z, c0.w, lane);
    aqA = wpb[0]; aqB = wpb[8];
  }
  for (int it = 0; it < itn; ++it){
    int4 cn = cp4[it + 2];                 // csr for it+2 (overrun lands in zeroed slack)
    uint4 nA0 = rowl(z, c1.x, lane), nA1 = rowl(z, c1.y, lane);
    uint4 nB0 = rowl(z, c1.z, lane), nB1 = rowl(z, c1.w, lane);
    unsigned naqA = wpb[(size_t)(2 * it + 2) * 8];
    unsigned naqB = wpb[(size_t)(2 * it + 3) * 8];
    DOTS8(zA0, zA1, aqA);
    DOTS8(zB0, zB1, aqB);
    zA0 = nA0; zA1 = nA1; zB0 = nB0; zB1 = nB1;
    aqA = naqA; aqB = naqB; c1 = cn;
  }
  float inv = 1.f / den1[(size_t)n * 8 + head];
  short8 o;
  #pragma unroll
  for (int j = 0; j < 8; j++) o[j] = (short)f2bf(elu(acc[j] * inv));
  *(short8*)(hcat + (size_t)n * DD + lane * 8) = o;
}

__global__ __launch_bounds__(256) void k_agg2(const u16* __restrict__ z,
    const unsigned* __restrict__ wp, const float* __restrict__ den2,
    const int* __restrict__ off, const int* __restrict__ csr,
    const u16* __restrict__ xb, float* __restrict__ out, int N){
  int wid = __builtin_amdgcn_readfirstlane(threadIdx.x >> 6);
  int lane = threadIdx.x & 63;
  int n = blockIdx.x * 4 + wid;
  if (n >= N) return;
  int o0 = off[n];
  int itn = (off[n + 1] - o0) >> 2;
  const int4* cp4 = (const int4*)(csr + o0);
  int pb = o0 >> 1;
  float acc[8];
  #pragma unroll
  for (int j = 0; j < 8; j++) acc[j] = 0.f;

  uint4 zA0, zA1, zB0, zB1;
  unsigned aqA, aqB;
  int4 c1;
  {
    int4 c0 = cp4[0];
    c1 = cp4[1];
    zA0 = rowl(z, c0.x, lane); zA1 = rowl(z, c0.y, lane);
    zB0 = rowl(z, c0.z, lane); zB1 = rowl(z, c0.w, lane);
    uint2 a01 = *(const uint2*)(wp + pb);
    aqA = a01.x; aqB = a01.y;
  }
  for (int it = 0; it < itn; ++it){
    int4 cn = cp4[it + 2];
    uint4 nA0 = rowl(z, c1.x, lane), nA1 = rowl(z, c1.y, lane);
    uint4 nB0 = rowl(z, c1.z, lane), nB1 = rowl(z, c1.w, lane);
    uint2 an = *(const uint2*)(wp + pb + 2 * it + 2);
    DOTS8(zA0, zA1, aqA);
    DOTS8(zB0, zB1, aqB);
    zA0 = nA0; zA1 = nA1; zB0 = nB0; zB1 = nB1;
    aqA = an.x; aqB = an.y; c1 = cn;
  }
  float inv = 1.f / den2[n];
  short8 xv = *(const short8*)(xb + (size_t)n * DD + lane * 8);
  float ov[8];
  #pragma unroll
  for (int j = 0; j < 8; j++) ov[j] = elu(acc[j] * inv) + bf2f((u16)xv[j]);
  float4 o0v, o1v;
  o0v.x = ov[0]; o0v.y = ov[1]; o0v.z = ov[2]; o0v.w = ov[3];
  o1v.x = ov[4]; o1v.y = ov[5]; o1v.z = ov[6]; o1v.w = ov[7];
  *(float4*)(out + (size_t)n * DD + lane * 8) = o0v;
  *(float4*)(out + (size_t)n * DD + lane * 8 + 4) = o1v;
}

// ---------------- launcher ----------------
extern "C" void kernel_launch(void* const* d_in, const int* in_sizes, int n_in,
                              void* d_out, int out_size, void* d_ws, size_t ws_size,
                              hipStream_t stream){
  const float* h   = (const float*)d_in[0];
  const float* W1  = (const float*)d_in[1];
  const float* a1  = (const float*)d_in[2];
  const float* Wout= (const float*)d_in[3];
  const float* aout= (const float*)d_in[4];
  const int* src   = (const int*)d_in[5];
  const int* dst   = (const int*)d_in[6];
  float* out = (float*)d_out;
  const int N = in_sizes[0] / DD;     // 16384
  const int E = in_sizes[5];          // 540672
  const int EP = E + 3 * N + 512;     // padded-CSR capacity (<=3 pads/node + prefetch slack)
  const int ep2 = EP >> 1;            // pair capacity

  char* p = (char*)d_ws;
  auto alloc = [&](size_t bytes) -> char* {
    char* r = p;
    p += (bytes + 255) & ~(size_t)255;
    return r;
  };
  u16* xb    = (u16*)alloc((size_t)N * DD * 2);
  u16* z1b   = (u16*)alloc((size_t)N * DD * 2);   // reused as z2b
  u16* hcat  = (u16*)alloc((size_t)N * DD * 2);
  u16* wbt1  = (u16*)alloc((size_t)DD * DD * 2);
  u16* wbt2  = (u16*)alloc((size_t)DD * DD * 2);
  float* es1 = (float*)alloc((size_t)N * HH * 4);
  float* ed1 = (float*)alloc((size_t)N * HH * 4);
  float* es2 = (float*)alloc((size_t)N * 4);
  float* ed2 = (float*)alloc((size_t)N * 4);
  float* den1= (float*)alloc((size_t)N * HH * 4);
  float* den2= (float*)alloc((size_t)N * 4);
  int* deg   = (int*)alloc((size_t)N * 4);
  int* off   = (int*)alloc((size_t)(N + 1) * 4);
  int* cursor= (int*)alloc((size_t)N * 4);
  int* csr   = (int*)alloc((size_t)EP * 4);
  unsigned* wp1 = (unsigned*)alloc(((size_t)ep2 * 8 + 64) * 4);  // [pair][head]
  unsigned* wp2 = (unsigned*)alloc(((size_t)ep2 + 64) * 4);

  // one memset covers deg..cursor (off is fully rewritten by k_scan; csr slack zeroed in k_scatter)
  hipMemsetAsync(deg, 0, (size_t)((char*)csr - (char*)deg), stream);

  int n4 = N * DD / 4;
  int prep_threads = n4 + HH * DD * DOO / 8 + DD * DD + E;
  k_prep<<<(prep_threads + 255) / 256, 256, 0, stream>>>(h, xb, W1, wbt1, Wout, wbt2, dst, deg, n4, E);
  k_scan<<<1, 1024, 0, stream>>>(deg, off, N);
  k_scatter<<<(E + 255) / 256, 256, 0, stream>>>(src, dst, off, cursor, csr, E, N);

  dim3 gg(DD / 128, N / 128);     // x = n-tile (4), y = m-tile (128): A-panel reuse
  dim3 ga((N + 3) / 4);

  k_gemm<<<gg, 256, 0, stream>>>(xb, wbt1, z1b, N);
  k_scores1<<<(N + 3) / 4, 256, 0, stream>>>(z1b, a1, es1, ed1, N);
  k_edgew1<<<ga, 256, 0, stream>>>(es1, ed1, off, deg, csr, wp1, den1, N);
  k_agg1<<<ga, 256, 0, stream>>>(z1b, wp1, den1, off, csr, hcat, N);

  k_gemm<<<gg, 256, 0, stream>>>(hcat, wbt2, z1b, N);
  k_scores2<<<(N + 3) / 4, 256, 0, stream>>>(z1b, aout, es2, ed2, N);
  k_edgew2<<<ga, 256, 0, stream>>>(es2, ed2, off, deg, csr, wp2, den2, N);
  k_agg2<<<ga, 256, 0, stream>>>(z1b, wp2, den2, off, csr, xb, out, N);
}

// Round 3
// 252.258 us; speedup vs baseline: 1.1151x; 1.1151x over previous
//
#include <hip/hip_runtime.h>
#include <stdint.h>

#define DD 512
#define HH 8
#define DOO 64
#define ALPHA 0.2f

typedef __attribute__((ext_vector_type(8))) short short8;
typedef __attribute__((ext_vector_type(4))) float floatx4;
typedef __attribute__((ext_vector_type(4))) unsigned short u16x4;
typedef unsigned short u16;

static __device__ __forceinline__ float bf2f(u16 u){
  union { unsigned int u; float f; } c; c.u = ((unsigned int)u) << 16; return c.f;
}
static __device__ __forceinline__ u16 f2bf(float f){
  union { float f; unsigned int u; } c; c.f = f;
  unsigned int u = c.u;
  unsigned int r = (u + 0x7FFFu + ((u >> 16) & 1u)) >> 16;
  return (u16)r;
}
static __device__ __forceinline__ float leaky(float s){ return (s >= 0.f) ? s : ALPHA * s; }
static __device__ __forceinline__ float elu(float v){ return (v > 0.f) ? v : (__expf(v) - 1.f); }

// pair (z0[c], z1[c]) bf16x2 from two edges' dwords (each dword = cols c,c+1 of one row)
// v_perm pool: sel 0-3 -> src1 bytes, 4-7 -> src0 bytes
#define PERM_LO 0x01000504u
#define PERM_HI 0x03020706u

#define DOT2(accv, pairv, wv) \
  asm("v_dot2_f32_bf16 %0, %1, %2, %0" : "+v"(accv) : "v"(pairv), "v"(wv))

#define GLOAD_LDS16(g, l) \
  __builtin_amdgcn_global_load_lds((const __attribute__((address_space(1))) void*)(g), \
                                   (__attribute__((address_space(3))) void*)(l), 16, 0, 0)

// ---------------- fused prep: x->bf16, W1 transpose, Wout transpose, degree count ----------------
__global__ void k_prep(const float* __restrict__ h, u16* __restrict__ xb,
                       const float* __restrict__ W1, u16* __restrict__ wbt1,
                       const float* __restrict__ Wout, u16* __restrict__ wbt2,
                       const int* __restrict__ dst, int* deg,
                       int n4, int E){
  int i = blockIdx.x * blockDim.x + threadIdx.x;
  if (i < n4){
    float4 v = ((const float4*)h)[i];
    u16x4 o;
    o[0] = f2bf(v.x); o[1] = f2bf(v.y); o[2] = f2bf(v.z); o[3] = f2bf(v.w);
    ((u16x4*)xb)[i] = o;
    return;
  }
  i -= n4;
  if (i < HH * DD * DOO / 8){
    int idx0 = i * 8;
    #pragma unroll
    for (int t = 0; t < 8; t++){
      int idx = idx0 + t;
      int hh = idx >> 15;
      int rem = idx & 32767;
      int k = rem >> 6;
      int dd = rem & 63;
      wbt1[(hh * 64 + dd) * DD + k] = f2bf(W1[idx]);
    }
    return;
  }
  i -= HH * DD * DOO / 8;
  if (i < DD * DD){
    int k = i >> 9, n = i & 511;
    wbt2[n * DD + k] = f2bf(Wout[i]);
    return;
  }
  i -= DD * DD;
  if (i < E) atomicAdd(&deg[dst[i]], 1);
}

// ---------------- CSR build (degrees padded to multiple of 4: no masks in agg) ----------------
__global__ void k_scan(const int* __restrict__ deg, int* __restrict__ off, int N){
  __shared__ int sm[1024];
  int tid = threadIdx.x;
  const int per = 16;
  int base = tid * per;
  int loc[per];
  int t = 0;
  #pragma unroll
  for (int i = 0; i < per; i++){
    int v = (base + i < N) ? deg[base + i] : 0;
    v = (v + 3) & ~3;                       // pad each node's edge list to multiple of 4
    loc[i] = v; t += v;
  }
  sm[tid] = t; __syncthreads();
  for (int o = 1; o < 1024; o <<= 1){
    int v = 0;
    if (tid >= o) v = sm[tid - o];
    __syncthreads();
    sm[tid] += v;
    __syncthreads();
  }
  int run = sm[tid] - t;
  #pragma unroll
  for (int i = 0; i < per; i++){ if (base + i < N) off[base + i] = run; run += loc[i]; }
  if (tid == 1023) off[N] = run;
}

__global__ void k_scatter(const int* __restrict__ src, const int* __restrict__ dst,
                          const int* __restrict__ off, int* cursor, int* __restrict__ csr,
                          int E, int N){
  int i = blockIdx.x * blockDim.x + threadIdx.x;
  if (i < 256){                             // zero the prefetch-overrun slack past off[N]
    csr[off[N] + i] = 0;
  }
  if (i < E){
    int d = dst[i];
    int p = atomicAdd(&cursor[d], 1);
    csr[off[d] + p] = src[i];
  }
}

// ---------------- bf16 MFMA GEMM: BK=64, XOR-swizzled LDS, n-fastest grid ----------------
__global__ __launch_bounds__(256) void k_gemm(const u16* __restrict__ A,
                                              const u16* __restrict__ BT,
                                              u16* __restrict__ C, int M){
  __shared__ __attribute__((aligned(16))) u16 As[128 * 64];
  __shared__ __attribute__((aligned(16))) u16 Bs[128 * 64];
  const int tid = threadIdx.x;
  const int wid = tid >> 6, lane = tid & 63;
  const int n0 = blockIdx.x * 128, m0 = blockIdx.y * 128;
  const int wr = wid >> 1, wc = wid & 1;
  const int row16 = lane & 15, kg = lane >> 4;
  floatx4 acc[4][4];
  #pragma unroll
  for (int i = 0; i < 4; i++)
    #pragma unroll
    for (int j = 0; j < 4; j++) acc[i][j] = (floatx4)0.0f;

  for (int kt = 0; kt < DD; kt += 64){
    #pragma unroll
    for (int i = 0; i < 4; i++){
      int chunk = i * 256 + tid;          // LDS granule 0..1023 (linear dest)
      int m = chunk >> 3, g = chunk & 7;
      int gs = g ^ (m & 7);               // inverse-swizzled global source granule
      GLOAD_LDS16(A + (size_t)(m0 + m) * DD + kt + gs * 8, &As[chunk * 8]);
      GLOAD_LDS16(BT + (size_t)(n0 + m) * DD + kt + gs * 8, &Bs[chunk * 8]);
    }
    __syncthreads();
    short8 af[4][2], bf[4][2];
    #pragma unroll
    for (int mi = 0; mi < 4; mi++)
      #pragma unroll
      for (int kk = 0; kk < 2; kk++){
        int row = wr * 64 + mi * 16 + row16;
        int gr = (kk * 4 + kg) ^ (row & 7);
        af[mi][kk] = *(const short8*)(&As[(row * 8 + gr) * 8]);
      }
    #pragma unroll
    for (int ni = 0; ni < 4; ni++)
      #pragma unroll
      for (int kk = 0; kk < 2; kk++){
        int row = wc * 64 + ni * 16 + row16;
        int gr = (kk * 4 + kg) ^ (row & 7);
        bf[ni][kk] = *(const short8*)(&Bs[(row * 8 + gr) * 8]);
      }
    #pragma unroll
    for (int kk = 0; kk < 2; kk++)
      #pragma unroll
      for (int mi = 0; mi < 4; mi++)
        #pragma unroll
        for (int ni = 0; ni < 4; ni++)
          acc[mi][ni] = __builtin_amdgcn_mfma_f32_16x16x32_bf16(af[mi][kk], bf[ni][kk], acc[mi][ni], 0, 0, 0);
    __syncthreads();
  }
  #pragma unroll
  for (int mi = 0; mi < 4; mi++)
    #pragma unroll
    for (int ni = 0; ni < 4; ni++)
      #pragma unroll
      for (int j = 0; j < 4; j++){
        int r = m0 + wr * 64 + mi * 16 + kg * 4 + j;
        int c = n0 + wc * 64 + ni * 16 + row16;
        C[(size_t)r * DD + c] = f2bf(acc[mi][ni][j]);
      }
}

// ---------------- attention scores ----------------
__global__ void k_scores1(const u16* __restrict__ z, const float* __restrict__ a1,
                          float* __restrict__ es, float* __restrict__ ed, int N){
  int wid = threadIdx.x >> 6, lane = threadIdx.x & 63;
  int n = blockIdx.x * 4 + wid;
  if (n >= N) return;
  int h = lane >> 3, j8 = lane & 7;
  short8 zv = *(const short8*)(z + (size_t)n * DD + lane * 8);
  float esv = 0.f, edv = 0.f;
  #pragma unroll
  for (int t = 0; t < 8; t++){
    float f = bf2f((u16)zv[t]);
    esv += f * a1[h * 128 + j8 * 8 + t];
    edv += f * a1[h * 128 + 64 + j8 * 8 + t];
  }
  #pragma unroll
  for (int d2 = 1; d2 < 8; d2 <<= 1){ esv += __shfl_xor(esv, d2); edv += __shfl_xor(edv, d2); }
  if (j8 == 0){ es[n * 8 + h] = esv; ed[n * 8 + h] = edv; }
}

__global__ void k_scores2(const u16* __restrict__ z, const float* __restrict__ aout,
                          float* __restrict__ es, float* __restrict__ ed, int N){
  int wid = threadIdx.x >> 6, lane = threadIdx.x & 63;
  int n = blockIdx.x * 4 + wid;
  if (n >= N) return;
  short8 zv = *(const short8*)(z + (size_t)n * DD + lane * 8);
  float esv = 0.f, edv = 0.f;
  #pragma unroll
  for (int t = 0; t < 8; t++){
    float f = bf2f((u16)zv[t]);
    esv += f * aout[lane * 8 + t];
    edv += f * aout[512 + lane * 8 + t];
  }
  #pragma unroll
  for (int d2 = 1; d2 < 64; d2 <<= 1){ esv += __shfl_xor(esv, d2); edv += __shfl_xor(edv, d2); }
  if (lane == 0){ es[n] = esv; ed[n] = edv; }
}

// ---------------- edge weights, hoisted out of aggregation ----------------
// One wave per node. w = exp(leaky(es[src]+ed[n])) per head; pack CSR pairs as bf16x2
// in [head][pair] layout (per-pass-contiguous weight stream in agg); pads w=0 src=0.
__global__ void k_edgew1(const float* __restrict__ es, const float* __restrict__ ed,
                         const int* __restrict__ off, const int* __restrict__ deg,
                         int* __restrict__ csr, unsigned* __restrict__ wp,
                         float* __restrict__ den1, int N, int ep2){
  int wid = threadIdx.x >> 6, lane = threadIdx.x & 63;
  int n = blockIdx.x * 4 + wid;
  if (n >= N) return;
  int o0 = off[n], cntp = off[n + 1] - o0, cnt = deg[n];
  float edh[8];
  {
    float4 d0 = *(const float4*)(ed + (size_t)n * 8);
    float4 d1 = *(const float4*)(ed + (size_t)n * 8 + 4);
    edh[0]=d0.x; edh[1]=d0.y; edh[2]=d0.z; edh[3]=d0.w;
    edh[4]=d1.x; edh[5]=d1.y; edh[6]=d1.z; edh[7]=d1.w;
  }
  float den[8];
  #pragma unroll
  for (int h = 0; h < 8; h++) den[h] = 0.f;
  for (int base = 0; base < cntp; base += 64){
    int e = base + lane;
    float wv[8];
    if (e < cnt){
      int s = csr[o0 + e];
      float4 e0 = *(const float4*)(es + (size_t)s * 8);
      float4 e1 = *(const float4*)(es + (size_t)s * 8 + 4);
      float ev[8] = {e0.x, e0.y, e0.z, e0.w, e1.x, e1.y, e1.z, e1.w};
      #pragma unroll
      for (int h = 0; h < 8; h++){
        float w = __expf(leaky(ev[h] + edh[h]));
        wv[h] = w; den[h] += w;
      }
    } else {
      if (e < cntp) csr[o0 + e] = 0;      // pad slot: valid gather target, zero weight
      #pragma unroll
      for (int h = 0; h < 8; h++) wv[h] = 0.f;
    }
    #pragma unroll
    for (int h = 0; h < 8; h++){
      float wn = __shfl_down(wv[h], 1);
      if (!(lane & 1) && e < cntp){
        unsigned pk;
        asm("v_cvt_pk_bf16_f32 %0, %1, %2" : "=v"(pk) : "v"(wv[h]), "v"(wn));
        wp[(size_t)h * ep2 + ((o0 + e) >> 1)] = pk;
      }
    }
  }
  #pragma unroll
  for (int h = 0; h < 8; h++){
    float d = den[h];
    #pragma unroll
    for (int d2 = 1; d2 < 64; d2 <<= 1) d += __shfl_xor(d, d2);
    if (lane == 0) den1[(size_t)n * 8 + h] = d;
  }
}

__global__ void k_edgew2(const float* __restrict__ es, const float* __restrict__ ed,
                         const int* __restrict__ off, const int* __restrict__ deg,
                         int* __restrict__ csr, unsigned* __restrict__ wp,
                         float* __restrict__ den2, int N){
  int wid = threadIdx.x >> 6, lane = threadIdx.x & 63;
  int n = blockIdx.x * 4 + wid;
  if (n >= N) return;
  int o0 = off[n], cntp = off[n + 1] - o0, cnt = deg[n];
  float edn = ed[n];
  float dsum = 0.f;
  for (int base = 0; base < cntp; base += 64){
    int e = base + lane;
    float w = 0.f;
    if (e < cnt){
      int s = csr[o0 + e];
      w = __expf(leaky(es[s] + edn));
      dsum += w;
    } else if (e < cntp){
      csr[o0 + e] = 0;
    }
    float wn = __shfl_down(w, 1);
    if (!(lane & 1) && e < cntp){
      unsigned pk;
      asm("v_cvt_pk_bf16_f32 %0, %1, %2" : "=v"(pk) : "v"(w), "v"(wn));
      wp[(o0 + e) >> 1] = pk;
    }
  }
  #pragma unroll
  for (int d2 = 1; d2 < 64; d2 <<= 1) dsum += __shfl_xor(dsum, d2);
  if (lane == 0) den2[n] = dsum;
}

// ---------------- column-tiled aggregation: wave-uniform rows, dword cols, L2-resident slice ----
// grid (N/4, 4); pass p covers cols [p*128, p*128+128) -> 4MB z-slice fits one XCD L2.
// Wave = one node; lane owns 2 cols (1 dword). Rows via s_load'd csr -> SALU base + lane voffset:
// zero per-iter VALU addressing. 2 pairs/iter, 2-iter-deep pipeline (8 gathers in flight).
__global__ __launch_bounds__(256) void k_agg1(const u16* __restrict__ z,
    const unsigned* __restrict__ wp, const float* __restrict__ den1,
    const int* __restrict__ off, const int* __restrict__ csr,
    u16* __restrict__ hcat, int N, int ep2){
  int wid = __builtin_amdgcn_readfirstlane(threadIdx.x >> 6);
  int lane = threadIdx.x & 63;
  int n = blockIdx.x * 4 + wid;
  if (n >= N) return;
  int p = blockIdx.y;
  int o0 = off[n];
  int itn = (off[n + 1] - o0) >> 2;        // 2 pairs (4 edges) per iteration, exact
  const int4* cp4 = (const int4*)(csr + o0);
  const unsigned* zd = (const unsigned*)z + (size_t)p * 64 + lane;   // + s*256 per row
  int head = 2 * p + (lane >> 5);          // lanes 0-31: cols p*128..+63 -> head 2p; 32-63 -> 2p+1
  const unsigned* wpb = wp + (size_t)head * ep2 + (o0 >> 1);         // [head][pair], o0>>1 even
  float acc0 = 0.f, acc1 = 0.f;

  int4 c0 = cp4[0], c1 = cp4[1];
  uint2 a0 = *(const uint2*)(wpb);
  uint2 a1 = *(const uint2*)(wpb + 2);
  unsigned dA0 = zd[(size_t)(unsigned)c0.x * 256], dA1 = zd[(size_t)(unsigned)c0.y * 256];
  unsigned dB0 = zd[(size_t)(unsigned)c0.z * 256], dB1 = zd[(size_t)(unsigned)c0.w * 256];
  unsigned eA0 = zd[(size_t)(unsigned)c1.x * 256], eA1 = zd[(size_t)(unsigned)c1.y * 256];
  unsigned eB0 = zd[(size_t)(unsigned)c1.z * 256], eB1 = zd[(size_t)(unsigned)c1.w * 256];

  for (int it = 0; it < itn; ++it){
    int4 cn = cp4[it + 2];                 // overrun lands in zeroed slack / next node (unused)
    uint2 an = *(const uint2*)(wpb + 2 * it + 4);
    unsigned nA0 = zd[(size_t)(unsigned)cn.x * 256], nA1 = zd[(size_t)(unsigned)cn.y * 256];
    unsigned nB0 = zd[(size_t)(unsigned)cn.z * 256], nB1 = zd[(size_t)(unsigned)cn.w * 256];
    unsigned pr;
    pr = __builtin_amdgcn_perm(dA0, dA1, PERM_LO); DOT2(acc0, pr, a0.x);
    pr = __builtin_amdgcn_perm(dA0, dA1, PERM_HI); DOT2(acc1, pr, a0.x);
    pr = __builtin_amdgcn_perm(dB0, dB1, PERM_LO); DOT2(acc0, pr, a0.y);
    pr = __builtin_amdgcn_perm(dB0, dB1, PERM_HI); DOT2(acc1, pr, a0.y);
    dA0 = eA0; dA1 = eA1; dB0 = eB0; dB1 = eB1; a0 = a1;
    eA0 = nA0; eA1 = nA1; eB0 = nB0; eB1 = nB1; a1 = an;
  }
  float inv = 1.f / den1[(size_t)n * 8 + head];
  unsigned od = (unsigned)f2bf(elu(acc0 * inv)) | ((unsigned)f2bf(elu(acc1 * inv)) << 16);
  ((unsigned*)(hcat + (size_t)n * DD))[p * 64 + lane] = od;
}

__global__ __launch_bounds__(256) void k_agg2(const u16* __restrict__ z,
    const unsigned* __restrict__ wp, const float* __restrict__ den2,
    const int* __restrict__ off, const int* __restrict__ csr,
    const u16* __restrict__ xb, float* __restrict__ out, int N){
  int wid = __builtin_amdgcn_readfirstlane(threadIdx.x >> 6);
  int lane = threadIdx.x & 63;
  int n = blockIdx.x * 4 + wid;
  if (n >= N) return;
  int p = blockIdx.y;
  int o0 = off[n];
  int itn = (off[n + 1] - o0) >> 2;
  const int4* cp4 = (const int4*)(csr + o0);
  const unsigned* zd = (const unsigned*)z + (size_t)p * 64 + lane;
  const unsigned* wpb = wp + (o0 >> 1);    // single head: wave-uniform weights
  float acc0 = 0.f, acc1 = 0.f;

  int4 c0 = cp4[0], c1 = cp4[1];
  uint2 a0 = *(const uint2*)(wpb);
  uint2 a1 = *(const uint2*)(wpb + 2);
  unsigned dA0 = zd[(size_t)(unsigned)c0.x * 256], dA1 = zd[(size_t)(unsigned)c0.y * 256];
  unsigned dB0 = zd[(size_t)(unsigned)c0.z * 256], dB1 = zd[(size_t)(unsigned)c0.w * 256];
  unsigned eA0 = zd[(size_t)(unsigned)c1.x * 256], eA1 = zd[(size_t)(unsigned)c1.y * 256];
  unsigned eB0 = zd[(size_t)(unsigned)c1.z * 256], eB1 = zd[(size_t)(unsigned)c1.w * 256];

  for (int it = 0; it < itn; ++it){
    int4 cn = cp4[it + 2];
    uint2 an = *(const uint2*)(wpb + 2 * it + 4);
    unsigned nA0 = zd[(size_t)(unsigned)cn.x * 256], nA1 = zd[(size_t)(unsigned)cn.y * 256];
    unsigned nB0 = zd[(size_t)(unsigned)cn.z * 256], nB1 = zd[(size_t)(unsigned)cn.w * 256];
    unsigned pr;
    pr = __builtin_amdgcn_perm(dA0, dA1, PERM_LO); DOT2(acc0, pr, a0.x);
    pr = __builtin_amdgcn_perm(dA0, dA1, PERM_HI); DOT2(acc1, pr, a0.x);
    pr = __builtin_amdgcn_perm(dB0, dB1, PERM_LO); DOT2(acc0, pr, a0.y);
    pr = __builtin_amdgcn_perm(dB0, dB1, PERM_HI); DOT2(acc1, pr, a0.y);
    dA0 = eA0; dA1 = eA1; dB0 = eB0; dB1 = eB1; a0 = a1;
    eA0 = nA0; eA1 = nA1; eB0 = nB0; eB1 = nB1; a1 = an;
  }
  float inv = 1.f / den2[n];
  unsigned xv = ((const unsigned*)(xb + (size_t)n * DD))[p * 64 + lane];
  float2 o2;
  o2.x = elu(acc0 * inv) + bf2f((u16)(xv & 0xFFFFu));
  o2.y = elu(acc1 * inv) + bf2f((u16)(xv >> 16));
  *(float2*)(out + (size_t)n * DD + p * 128 + lane * 2) = o2;
}

// ---------------- launcher ----------------
extern "C" void kernel_launch(void* const* d_in, const int* in_sizes, int n_in,
                              void* d_out, int out_size, void* d_ws, size_t ws_size,
                              hipStream_t stream){
  const float* h   = (const float*)d_in[0];
  const float* W1  = (const float*)d_in[1];
  const float* a1  = (const float*)d_in[2];
  const float* Wout= (const float*)d_in[3];
  const float* aout= (const float*)d_in[4];
  const int* src   = (const int*)d_in[5];
  const int* dst   = (const int*)d_in[6];
  float* out = (float*)d_out;
  const int N = in_sizes[0] / DD;     // 16384
  const int E = in_sizes[5];          // 540672
  const int EP = E + 3 * N + 512;     // padded-CSR capacity (<=3 pads/node + prefetch slack)
  const int ep2 = EP >> 1;            // pair capacity

  char* p = (char*)d_ws;
  auto alloc = [&](size_t bytes) -> char* {
    char* r = p;
    p += (bytes + 255) & ~(size_t)255;
    return r;
  };
  u16* xb    = (u16*)alloc((size_t)N * DD * 2);
  u16* z1b   = (u16*)alloc((size_t)N * DD * 2);   // reused as z2b
  u16* hcat  = (u16*)alloc((size_t)N * DD * 2);
  u16* wbt1  = (u16*)alloc((size_t)DD * DD * 2);
  u16* wbt2  = (u16*)alloc((size_t)DD * DD * 2);
  float* es1 = (float*)alloc((size_t)N * HH * 4);
  float* ed1 = (float*)alloc((size_t)N * HH * 4);
  float* es2 = (float*)alloc((size_t)N * 4);
  float* ed2 = (float*)alloc((size_t)N * 4);
  float* den1= (float*)alloc((size_t)N * HH * 4);
  float* den2= (float*)alloc((size_t)N * 4);
  int* deg   = (int*)alloc((size_t)N * 4);
  int* off   = (int*)alloc((size_t)(N + 1) * 4);
  int* cursor= (int*)alloc((size_t)N * 4);
  int* csr   = (int*)alloc((size_t)EP * 4);
  unsigned* wp1 = (unsigned*)alloc(((size_t)HH * ep2 + 64) * 4);  // [head][pair]
  unsigned* wp2 = (unsigned*)alloc(((size_t)ep2 + 64) * 4);

  // one memset covers deg..cursor (off is fully rewritten by k_scan; csr slack zeroed in k_scatter)
  hipMemsetAsync(deg, 0, (size_t)((char*)csr - (char*)deg), stream);

  int n4 = N * DD / 4;
  int prep_threads = n4 + HH * DD * DOO / 8 + DD * DD + E;
  k_prep<<<(prep_threads + 255) / 256, 256, 0, stream>>>(h, xb, W1, wbt1, Wout, wbt2, dst, deg, n4, E);
  k_scan<<<1, 1024, 0, stream>>>(deg, off, N);
  k_scatter<<<(E + 255) / 256, 256, 0, stream>>>(src, dst, off, cursor, csr, E, N);

  dim3 gg(DD / 128, N / 128);     // x = n-tile (4), y = m-tile (128): A-panel reuse
  dim3 ga((N + 3) / 4, 4);        // x fastest -> all blocks of pass p run before pass p+1
  dim3 gw((N + 3) / 4);

  k_gemm<<<gg, 256, 0, stream>>>(xb, wbt1, z1b, N);
  k_scores1<<<(N + 3) / 4, 256, 0, stream>>>(z1b, a1, es1, ed1, N);
  k_edgew1<<<gw, 256, 0, stream>>>(es1, ed1, off, deg, csr, wp1, den1, N, ep2);
  k_agg1<<<ga, 256, 0, stream>>>(z1b, wp1, den1, off, csr, hcat, N, ep2);

  k_gemm<<<gg, 256, 0, stream>>>(hcat, wbt2, z1b, N);
  k_scores2<<<(N + 3) / 4, 256, 0, stream>>>(z1b, aout, es2, ed2, N);
  k_edgew2<<<gw, 256, 0, stream>>>(es2, ed2, off, deg, csr, wp2, den2, N);
  k_agg2<<<ga, 256, 0, stream>>>(z1b, wp2, den2, off, csr, xb, out, N);
}